// Round 13
// baseline (378.262 us; speedup 1.0000x reference)
//
#include <hip/hip_runtime.h>

#define NB 256
#define NT 1024

// native vector type for nontemporal builtins (HIP float4 is a struct -> rejected)
typedef float vf4 __attribute__((ext_vector_type(4)));

// ---- ws float offsets ----
#define O_CNT 0       // 128 ints (aliased onto floats 0..127)
#define O_AXB 256     // x-half dot + bh cache, 4096
#define O_P0  4608    // parity-0 A-partials (2 x 4096)
#define O_Q0  12800   // parity-1 A-partials (2 x 4096)

// Swizzled LDS index: +1 dword pad every 32 -> 2-way bank alias only (free).
__device__ __forceinline__ int zi(int c) { return c + (c >> 5); }

__global__ __launch_bounds__(128) void k_zero(int* __restrict__ cnt) {
    cnt[threadIdx.x] = 0;
}

// One persistent cooperative kernel; flag-sync (1-phase release counter per
// step). RELEASE ORDER (r12 bug fix): __syncthreads() FIRST (drains every
// wave's partial stores, vmcnt(0)), THEN leader threadfence + agent-release
// add. Acquire: leader agent-acquire load (L1/L2 inv) + __syncthreads().
// All dot orders bit-identical to r9/r10 -> same halting trajectory.
__global__ __launch_bounds__(NT) void act_all(
    const float* __restrict__ x, const float* __restrict__ s,
    const float* __restrict__ Wh, const float* __restrict__ bh,
    const float* __restrict__ Whalt, const float* __restrict__ bhalt,
    const float* __restrict__ Wo, const float* __restrict__ bo,
    float* __restrict__ out, float* __restrict__ wsb)
{
    const int tid  = threadIdx.x;
    const int lane = tid & 63;
    const int wid  = tid >> 6;
    const int row  = blockIdx.x * 16 + wid;      // 0..4095

    int* cnt = (int*)wsb;                        // O_CNT
    __shared__ float zb[4225];
    __shared__ float red[16];

    const int pre = (4 - ((row + 1) & 3)) & 3;   // (row*8193+start)%4, start%4==1
    const float* WhR = Wh + (size_t)row * 8193;

    // ================= step 0: full Wh row, cache x-half =================
    for (int k = tid; k < 4096; k += NT) zb[zi(k)] = x[k];
    __syncthreads();
    {   // x-half (cols 1..4096): never re-read -> nontemporal
        const int start = 1, n4h = (4096 - pre) >> 2;
        const vf4* W4 = (const vf4*)(WhR + start + pre);
        float a0=0.f, a1=0.f, a2=0.f, a3=0.f;
        if (lane < pre) a0 = WhR[start + lane] * zb[zi(lane)];
        #pragma unroll 8
        for (int j = lane; j < n4h; j += 64) {
            vf4 wv = __builtin_nontemporal_load(W4 + j);
            int c = pre + 4 * j;
            a0 += wv[0] * zb[zi(c)];   a1 += wv[1] * zb[zi(c + 1)];
            a2 += wv[2] * zb[zi(c + 2)]; a3 += wv[3] * zb[zi(c + 3)];
        }
        for (int c = pre + 4 * n4h + lane; c < 4096; c += 64)
            a0 += WhR[start + c] * zb[zi(c)];
        float acc = (a0 + a1) + (a2 + a3);
        #pragma unroll
        for (int off = 32; off; off >>= 1) acc += __shfl_xor(acc, off, 64);
        if (lane == 0) {
            wsb[O_AXB + row] = acc + bh[row];    // cached x-half (+bias)
            wsb[O_P0 + row]  = acc + WhR[0];     // step-0 partial incl. flag col
        }
    }
    __syncthreads();
    for (int k = tid; k < 4096; k += NT) zb[zi(k)] = s[k];
    __syncthreads();
    {   // s-half (cols 4097..8192): re-read each step -> normal loads
        const int start = 4097, n4h = (4096 - pre) >> 2;
        const float4* W4 = (const float4*)(WhR + start + pre);
        float a0=0.f, a1=0.f, a2=0.f, a3=0.f;
        if (lane < pre) a0 = WhR[start + lane] * zb[zi(lane)];
        #pragma unroll 8
        for (int j = lane; j < n4h; j += 64) {
            float4 wv = W4[j];
            int c = pre + 4 * j;
            a0 += wv.x * zb[zi(c)];   a1 += wv.y * zb[zi(c + 1)];
            a2 += wv.z * zb[zi(c + 2)]; a3 += wv.w * zb[zi(c + 3)];
        }
        for (int c = pre + 4 * n4h + lane; c < 4096; c += 64)
            a0 += WhR[start + c] * zb[zi(c)];
        float acc = (a0 + a1) + (a2 + a3);
        #pragma unroll
        for (int off = 32; off; off >>= 1) acc += __shfl_xor(acc, off, 64);
        if (lane == 0) wsb[O_P0 + 4096 + row] = acc;
    }
    __syncthreads();                              // ALL waves' pb/AXB stores drained
    if (tid == 0) {
        __threadfence();
        __hip_atomic_fetch_add(&cnt[0], 1, __ATOMIC_RELEASE, __HIP_MEMORY_SCOPE_AGENT);
    }

    // loop-invariant vectors -> registers (kills 32KB/block/step of re-reads)
    const float4 hw  = ((const float4*)Whalt)[tid];
    const float4 bb1 = ((const float4*)bh)[tid];
    float4 bbA;                                   // AXB, loaded once at i==2
    const float bhalt0 = bhalt[0];

    float cum = 0.f, wsum = 0.f, ponder = 0.f;
    float4 accH; accH.x = accH.y = accH.z = accH.w = 0.f;

    // ================= halting loop =================
    for (int i = 1; i < 129; ++i) {
        if (tid == 0) {
            while (__hip_atomic_load(&cnt[i - 1], __ATOMIC_ACQUIRE,
                                     __HIP_MEMORY_SCOPE_AGENT) < NB)
                __builtin_amdgcn_s_sleep(2);
        }
        __syncthreads();                          // partials of step i-1 visible

        if (i == 2) bbA = ((const float4*)(wsb + O_AXB))[tid];
        const float* pbR = wsb + (((i - 1) & 1) ? O_Q0 : O_P0);
        float4 u0 = ((const float4*)pbR)[tid];
        float4 u1 = ((const float4*)(pbR + 4096))[tid];
        float4 bbv = (i == 1) ? bb1 : bbA;
        float4 nsv;
        nsv.x = u0.x + u1.x + bbv.x;  nsv.y = u0.y + u1.y + bbv.y;
        nsv.z = u0.z + u1.z + bbv.z;  nsv.w = u0.w + u1.w + bbv.w;
        { int c = 4 * tid;                        // stage full ns into LDS
          zb[zi(c)]   = nsv.x; zb[zi(c+1)] = nsv.y;
          zb[zi(c+2)] = nsv.z; zb[zi(c+3)] = nsv.w; }
        float part = hw.x*nsv.x + hw.y*nsv.y + hw.z*nsv.z + hw.w*nsv.w;
        #pragma unroll
        for (int off = 32; off; off >>= 1) part += __shfl_xor(part, off, 64);
        if (lane == 0) red[wid] = part;
        __syncthreads();                          // zb(ns) + red ready
        float logit = bhalt0;
        #pragma unroll
        for (int j = 0; j < 16; ++j) logit += red[j];   // identical everywhere
        const float p         = 1.0f / (1.0f + expf(-logit));
        const bool  will_halt = (cum + p >= 0.99f) || ((i - 1) == 127);
        const float w         = will_halt ? (1.0f - cum) : p;

        accH.x += w * nsv.x; accH.y += w * nsv.y;
        accH.z += w * nsv.z; accH.w += w * nsv.w;
        wsum += w;
        if (will_halt) { ponder = (float)(i - 1) + 1.0f + (1.0f - cum); break; }
        cum += p;

        // ---- A(i): both state quarters (order == r10, bit-identical) ----
        float* pbW = wsb + ((i & 1) ? O_Q0 : O_P0);
        #pragma unroll
        for (int q = 0; q < 2; ++q) {
            const int startq = 4097 + 2048 * q;
            const int zo     = 2048 * q;
            const int n4q    = (2048 - pre) >> 2;
            const float4* W4 = (const float4*)(WhR + startq + pre);
            float a0=0.f, a1=0.f, a2=0.f, a3=0.f;
            if (lane < pre) a0 = WhR[startq + lane] * zb[zi(zo + lane)];
            #pragma unroll 8
            for (int j = lane; j < n4q; j += 64) {
                float4 wv = W4[j];
                int c = zo + pre + 4 * j;
                a0 += wv.x * zb[zi(c)];   a1 += wv.y * zb[zi(c + 1)];
                a2 += wv.z * zb[zi(c + 2)]; a3 += wv.w * zb[zi(c + 3)];
            }
            for (int c2 = pre + 4 * n4q + lane; c2 < 2048; c2 += 64)
                a0 += WhR[startq + c2] * zb[zi(zo + c2)];
            float acc = (a0 + a1) + (a2 + a3);
            #pragma unroll
            for (int off = 32; off; off >>= 1) acc += __shfl_xor(acc, off, 64);
            if (lane == 0) pbW[(q << 12) + row] = acc;
        }
        __syncthreads();                          // ALL waves' pbW stores drained
        if (tid == 0) {
            __threadfence();
            __hip_atomic_fetch_add(&cnt[i], 1, __ATOMIC_RELEASE,
                                   __HIP_MEMORY_SCOPE_AGENT);
        }
    }

    // ================= epilogue: out = Wo @ hid + wsum*bo =================
    __syncthreads();                              // all waves past the break
    { int c = 4 * tid;                            // zb <- hid (every block has it)
      zb[zi(c)]   = accH.x; zb[zi(c+1)] = accH.y;
      zb[zi(c+2)] = accH.z; zb[zi(c+3)] = accH.w; }
    __syncthreads();
    const vf4* Wo4 = (const vf4*)(Wo + (size_t)row * 4096);
    float b0=0.f, b1=0.f, b2=0.f, b3=0.f;
    #pragma unroll 8
    for (int j = lane; j < 1024; j += 64) {
        vf4 wv = __builtin_nontemporal_load(Wo4 + j);
        int c = 4 * j;
        b0 += wv[0] * zb[zi(c)];   b1 += wv[1] * zb[zi(c + 1)];
        b2 += wv[2] * zb[zi(c + 2)]; b3 += wv[3] * zb[zi(c + 3)];
    }
    float acc = (b0 + b1) + (b2 + b3);
    #pragma unroll
    for (int off = 32; off; off >>= 1) acc += __shfl_xor(acc, off, 64);
    if (lane == 0) out[row] = acc + wsum * bo[row];

    if (blockIdx.x == 0) {                        // hid + ponder
        ((float4*)(out + 4096))[tid] = accH;
        if (tid == 0) out[8192] = ponder;
    }
}

extern "C" void kernel_launch(void* const* d_in, const int* in_sizes, int n_in,
                              void* d_out, int out_size, void* d_ws, size_t ws_size,
                              hipStream_t stream) {
    const float* x     = (const float*)d_in[0];
    const float* s     = (const float*)d_in[1];
    const float* Wh    = (const float*)d_in[2];
    const float* bh    = (const float*)d_in[3];
    const float* Whalt = (const float*)d_in[4];
    const float* bhalt = (const float*)d_in[5];
    const float* Wo    = (const float*)d_in[6];
    const float* bo    = (const float*)d_in[7];
    float* out = (float*)d_out;
    float* wsb = (float*)d_ws;

    k_zero<<<1, 128, 0, stream>>>((int*)wsb);

    void* args[] = { (void*)&x, (void*)&s, (void*)&Wh, (void*)&bh,
                     (void*)&Whalt, (void*)&bhalt, (void*)&Wo, (void*)&bo,
                     (void*)&out, (void*)&wsb };
    hipLaunchCooperativeKernel((void*)act_all, dim3(NB), dim3(NT),
                               args, 0, stream);
}

// Round 14
// 216.849 us; speedup vs baseline: 1.7444x; 1.7444x over previous
//
#include <hip/hip_runtime.h>
#include <hip/hip_cooperative_groups.h>

namespace cg = cooperative_groups;

#define K_PRE 6   // device-gated pre-launched steps (bench data halts at T~3-4)
#define NB 256
#define NT 1024

// ---- ws float offsets ----
#define O_CUM    0      // cum after step j, 128 slots
#define O_DONE   128    // done after step j, 128 slots
#define O_WSUM   256
#define O_PONDER 257
#define O_AXB    512    // x-half dot + bh cache, 4096
#define O_P0     4608   // parity-0 A-partials, 4096
#define O_Q0     12800  // parity-1 A-partials, 4096
#define O_ACCH   20992  // hid accumulator, 4096
#define O_NS0    25088  // tail handoff state
#define O_NS1    29184

// Swizzled LDS index: +1 dword pad every 32 -> 2-way bank alias only (free).
__device__ __forceinline__ int zi(int c) { return c + (c >> 5); }

// ---------- k_step(i): [ns(i-1)+halt(i-1) redundant] + [A(i), BLOCK-COOPERATIVE] ----------
// 256 blocks x 1024 thr, 1 block/CU. A(i) reads rows block-cooperatively:
// all 1024 threads burst one 16KB row segment -> 256 sequential DRAM streams
// (page-local) instead of 4096 interleaved wave-streams (the 2.2 TB/s wall).
__global__ __launch_bounds__(NT) void k_step(
    int i,
    const float* __restrict__ x, const float* __restrict__ s,
    const float* __restrict__ Wh, const float* __restrict__ bh,
    const float* __restrict__ Whalt, const float* __restrict__ bhalt,
    float* __restrict__ wsb)
{
    const int tid  = threadIdx.x;
    const int lane = tid & 63;
    const int wid  = tid >> 6;

    __shared__ float zb1[4225];
    __shared__ float zb2[4225];
    __shared__ float redH[16];
    __shared__ float redR[16][16];

    float* pbW = wsb + ((i & 1) ? O_Q0 : O_P0);

    if (i == 0) {
        // zb1 <- x, zb2 <- s
        for (int k = tid; k < 4096; k += NT) { zb1[zi(k)] = x[k]; zb2[zi(k)] = s[k]; }
        __syncthreads();
        // 16 rows in 4 groups of 4; per row: x-part [1,4097) and s-part [4097,8193)
        for (int g = 0; g < 4; ++g) {
            float4 wx[4], wsv[4];
            float  px[4], ps[4];
            int    pres[4], n4s[4];
            #pragma unroll
            for (int rr = 0; rr < 4; ++rr) {
                const int row = blockIdx.x * 16 + g * 4 + rr;
                const int pre = (4 - ((row + 1) & 3)) & 3;   // both parts share pre
                const int n4  = (4096 - pre) >> 2;
                pres[rr] = pre; n4s[rr] = n4;
                const float* base = Wh + (size_t)row * 8193;
                if (tid < n4) {
                    wx[rr]  = *(const float4*)(base + 1    + pre + 4 * tid);
                    wsv[rr] = *(const float4*)(base + 4097 + pre + 4 * tid);
                }
            }
            #pragma unroll
            for (int rr = 0; rr < 4; ++rr) {
                float ax = 0.f, as = 0.f;
                const int pre = pres[rr], n4 = n4s[rr];
                if (tid < n4) {
                    const int u = pre + 4 * tid;
                    ax = wx[rr].x*zb1[zi(u)]   + wx[rr].y*zb1[zi(u+1)]
                       + wx[rr].z*zb1[zi(u+2)] + wx[rr].w*zb1[zi(u+3)];
                    as = wsv[rr].x*zb2[zi(u)]   + wsv[rr].y*zb2[zi(u+1)]
                       + wsv[rr].z*zb2[zi(u+2)] + wsv[rr].w*zb2[zi(u+3)];
                }
                if (tid == 1008 + rr) {          // peel + tail scalars, this row
                    const float* base = Wh + (size_t)(blockIdx.x*16 + g*4 + rr) * 8193;
                    for (int u = 0; u < pre; ++u)
                        { ax += base[1+u]*zb1[zi(u)]; as += base[4097+u]*zb2[zi(u)]; }
                    for (int u = pre + 4*n4; u < 4096; ++u)
                        { ax += base[1+u]*zb1[zi(u)]; as += base[4097+u]*zb2[zi(u)]; }
                }
                px[rr] = ax; ps[rr] = as;
            }
            #pragma unroll
            for (int rr = 0; rr < 4; ++rr) {
                #pragma unroll
                for (int off = 32; off; off >>= 1) {
                    px[rr] += __shfl_xor(px[rr], off, 64);
                    ps[rr] += __shfl_xor(ps[rr], off, 64);
                }
                if (lane == 0) { redR[rr][wid] = px[rr]; redR[8 + rr][wid] = ps[rr]; }
            }
            __syncthreads();
            if (tid < 4) {
                float xd = 0.f, sd = 0.f;
                #pragma unroll
                for (int j2 = 0; j2 < 16; ++j2) { xd += redR[tid][j2]; sd += redR[8+tid][j2]; }
                const int row = blockIdx.x * 16 + g * 4 + tid;
                wsb[O_AXB + row] = xd + bh[row];                       // x-half (+bias) cache
                pbW[row] = (xd + sd) + Wh[(size_t)row * 8193];         // + flag col (step 0)
            }
            __syncthreads();                      // redR reuse next group
        }
        return;
    }

    // ---- idle fast path keeps the scalar chain alive ----
    const float doneB = (i >= 2) ? wsb[O_DONE + i - 2] : 0.0f;
    if (doneB != 0.0f) {
        if (blockIdx.x == 0 && tid == 0) {
            wsb[O_CUM + i - 1]  = wsb[O_CUM + i - 2];
            wsb[O_DONE + i - 1] = 1.0f;
        }
        return;
    }
    const float cumB = (i >= 2) ? wsb[O_CUM + i - 2] : 0.0f;

    // ---- ns(i-1) = pb + bias; halt logit (redundant per block) ----
    const float* pbR  = wsb + (((i - 1) & 1) ? O_Q0 : O_P0);
    const float* bias = (i == 1) ? bh : (wsb + O_AXB);     // AXB includes bh
    float4 u0 = ((const float4*)pbR)[tid];
    float4 bb = ((const float4*)bias)[tid];
    float4 hw = ((const float4*)Whalt)[tid];
    float4 nsv;
    nsv.x = u0.x + bb.x;  nsv.y = u0.y + bb.y;
    nsv.z = u0.z + bb.z;  nsv.w = u0.w + bb.w;
    { int c = 4 * tid;                            // stage full ns into LDS
      zb1[zi(c)]   = nsv.x; zb1[zi(c+1)] = nsv.y;
      zb1[zi(c+2)] = nsv.z; zb1[zi(c+3)] = nsv.w; }
    float part = hw.x*nsv.x + hw.y*nsv.y + hw.z*nsv.z + hw.w*nsv.w;
    #pragma unroll
    for (int off = 32; off; off >>= 1) part += __shfl_xor(part, off, 64);
    if (lane == 0) redH[wid] = part;
    __syncthreads();                              // zb1(ns) + redH ready
    float logit = bhalt[0];
    #pragma unroll
    for (int j = 0; j < 16; ++j) logit += redH[j];     // identical everywhere
    const float p         = 1.0f / (1.0f + expf(-logit));
    const bool  will_halt = (cumB + p >= 0.99f) || ((i - 1) == 127);
    const float w         = will_halt ? (1.0f - cumB) : p;

    if (blockIdx.x == 0 && tid == 0) {
        wsb[O_CUM + i - 1]  = cumB + p;
        wsb[O_DONE + i - 1] = will_halt ? 1.0f : 0.0f;
        if (i == 1) wsb[O_WSUM] = w; else wsb[O_WSUM] += w;
        if (will_halt) wsb[O_PONDER] = (float)(i - 1) + 1.0f + (1.0f - cumB);
    }
    if (blockIdx.x == 0) {                        // hid accumulator, block 0
        float4* aH = reinterpret_cast<float4*>(wsb + O_ACCH);
        if (i == 1) {
            float4 t; t.x = w*nsv.x; t.y = w*nsv.y; t.z = w*nsv.z; t.w = w*nsv.w;
            aH[tid] = t;
        } else {
            float4 t = aH[tid];
            t.x += w*nsv.x; t.y += w*nsv.y; t.z += w*nsv.z; t.w += w*nsv.w;
            aH[tid] = t;
        }
    }
    if (i == K_PRE && blockIdx.x == 1)            // handoff for coop tail
        reinterpret_cast<float4*>(wsb + (((i - 1) & 1) ? O_NS1 : O_NS0))[tid] = nsv;

    // ---- A(i): 16 rows block-cooperative, 2 groups of 8 (state-half only) ----
    if (i < K_PRE && !will_halt) {
        for (int g = 0; g < 2; ++g) {
            float4 wv[8];
            float  prt[8];
            int    pres[8], n4s[8];
            #pragma unroll
            for (int rr = 0; rr < 8; ++rr) {
                const int row = blockIdx.x * 16 + g * 8 + rr;
                const int pre = (4 - ((row + 1) & 3)) & 3;
                const int n4  = (4096 - pre) >> 2;
                pres[rr] = pre; n4s[rr] = n4;
                if (tid < n4)
                    wv[rr] = *(const float4*)(Wh + (size_t)row * 8193 + 4097 + pre + 4 * tid);
            }
            #pragma unroll
            for (int rr = 0; rr < 8; ++rr) {
                float a = 0.f;
                const int pre = pres[rr], n4 = n4s[rr];
                if (tid < n4) {
                    const int u = pre + 4 * tid;
                    a = wv[rr].x*zb1[zi(u)]   + wv[rr].y*zb1[zi(u+1)]
                      + wv[rr].z*zb1[zi(u+2)] + wv[rr].w*zb1[zi(u+3)];
                }
                if (tid == 1016 + rr) {           // peel + tail scalars
                    const float* base = Wh + (size_t)(blockIdx.x*16 + g*8 + rr) * 8193 + 4097;
                    for (int u = 0; u < pre; ++u)            a += base[u] * zb1[zi(u)];
                    for (int u = pre + 4*n4; u < 4096; ++u)  a += base[u] * zb1[zi(u)];
                }
                prt[rr] = a;
            }
            #pragma unroll
            for (int rr = 0; rr < 8; ++rr) {
                #pragma unroll
                for (int off = 32; off; off >>= 1) prt[rr] += __shfl_xor(prt[rr], off, 64);
                if (lane == 0) redR[rr][wid] = prt[rr];
            }
            __syncthreads();
            if (tid < 8) {
                float d = 0.f;
                #pragma unroll
                for (int j2 = 0; j2 < 16; ++j2) d += redR[tid][j2];
                pbW[blockIdx.x * 16 + g * 8 + tid] = d;
            }
            if (g == 0) __syncthreads();          // redR reuse
        }
    }
}

// ---------- cooperative tail for T > K_PRE (instant uniform exit on bench data) ----------
__global__ __launch_bounds__(NT, 4) void k_tail(
    const float* __restrict__ x, const float* __restrict__ Wh,
    const float* __restrict__ bh, const float* __restrict__ Whalt,
    const float* __restrict__ bhalt, float* __restrict__ wsb)
{
    cg::grid_group grid = cg::this_grid();
    if (wsb[O_DONE + K_PRE - 1] != 0.0f) return;

    const int tid  = threadIdx.x;
    const int lane = tid & 63;
    const int wid  = tid >> 6;
    const int gw   = blockIdx.x * 16 + wid;

    float* ns0 = wsb + O_NS0;
    float* ns1 = wsb + O_NS1;

    __shared__ float xl[4096];
    __shared__ float red[16];
    for (int k = tid; k < 4096; k += NT) xl[k] = x[k];
    __syncthreads();

    const float* WhR   = Wh + (size_t)gw * 8193;
    const float4* wh4  = reinterpret_cast<const float4*>(Whalt);
    const float bh_r   = bh[gw];
    const float bhalt0 = bhalt[0];

    float cum = wsb[O_CUM + K_PRE - 1];
    float wsuml = 0.f, ponder = 0.f;

    for (int i = K_PRE; i < 128; ++i) {
        const float* st = (i & 1) ? ns0 : ns1;
        float*      nsc = (i & 1) ? ns1 : ns0;

        float acc = 0.0f;
        #pragma unroll 8
        for (int k = lane; k < 4096; k += 64) acc += WhR[1 + k] * xl[k];
        #pragma unroll 8
        for (int k = lane; k < 4096; k += 64) acc += WhR[4097 + k] * st[k];
        #pragma unroll
        for (int off = 32; off; off >>= 1) acc += __shfl_xor(acc, off, 64);
        if (lane == 0) nsc[gw] = acc + bh_r;
        grid.sync();

        const float4* ns4 = reinterpret_cast<const float4*>(nsc);
        float4 nv = ns4[tid], hw = wh4[tid];
        float part = hw.x*nv.x + hw.y*nv.y + hw.z*nv.z + hw.w*nv.w;
        #pragma unroll
        for (int off = 32; off; off >>= 1) part += __shfl_xor(part, off, 64);
        if (lane == 0) red[wid] = part;
        __syncthreads();
        float logit = bhalt0;
        #pragma unroll
        for (int j = 0; j < 16; ++j) logit += red[j];
        const float p         = 1.0f / (1.0f + expf(-logit));
        const bool  will_halt = (cum + p >= 0.99f) || (i == 127);
        const float w         = will_halt ? (1.0f - cum) : p;

        if (blockIdx.x == 0) {                     // hid accumulator
            float4* aH = reinterpret_cast<float4*>(wsb + O_ACCH);
            float4 t = aH[tid];
            t.x += w*nv.x; t.y += w*nv.y; t.z += w*nv.z; t.w += w*nv.w;
            aH[tid] = t;
        }
        wsuml += w;

        if (will_halt) { ponder = (float)i + 1.0f + (1.0f - cum); break; }
        cum += p;
        grid.sync();
    }

    if (blockIdx.x == 0 && tid == 0) {
        wsb[O_WSUM]  += wsuml;
        wsb[O_PONDER] = ponder;
    }
}

// ---------- k_out: out = Wo @ hid + wsum*bo (Wo once, block-cooperative) ----------
__global__ __launch_bounds__(NT) void k_out(
    const float* __restrict__ Wo, const float* __restrict__ bo,
    const float* __restrict__ wsb, float* __restrict__ out)
{
    const int tid  = threadIdx.x;
    const int lane = tid & 63;
    const int wid  = tid >> 6;

    __shared__ float zb1[4225];
    __shared__ float redR[16][16];
    for (int k = tid; k < 4096; k += NT) zb1[zi(k)] = wsb[O_ACCH + k];
    __syncthreads();

    const float wsum = wsb[O_WSUM];
    for (int g = 0; g < 2; ++g) {
        float4 wv[8];
        float  prt[8];
        #pragma unroll
        for (int rr = 0; rr < 8; ++rr) {
            const int row = blockIdx.x * 16 + g * 8 + rr;
            wv[rr] = ((const float4*)(Wo + (size_t)row * 4096))[tid];   // aligned, n4=1024
        }
        #pragma unroll
        for (int rr = 0; rr < 8; ++rr) {
            const int u = 4 * tid;
            prt[rr] = wv[rr].x*zb1[zi(u)]   + wv[rr].y*zb1[zi(u+1)]
                    + wv[rr].z*zb1[zi(u+2)] + wv[rr].w*zb1[zi(u+3)];
        }
        #pragma unroll
        for (int rr = 0; rr < 8; ++rr) {
            #pragma unroll
            for (int off = 32; off; off >>= 1) prt[rr] += __shfl_xor(prt[rr], off, 64);
            if (lane == 0) redR[rr][wid] = prt[rr];
        }
        __syncthreads();
        if (tid < 8) {
            float d = 0.f;
            #pragma unroll
            for (int j2 = 0; j2 < 16; ++j2) d += redR[tid][j2];
            const int row = blockIdx.x * 16 + g * 8 + tid;
            out[row] = d + wsum * bo[row];
        }
        if (g == 0) __syncthreads();
    }

    const int gtid = blockIdx.x * NT + tid;
    if (gtid < 4096) out[4096 + gtid] = wsb[O_ACCH + gtid];
    if (gtid == 0)   out[8192] = wsb[O_PONDER];
}

extern "C" void kernel_launch(void* const* d_in, const int* in_sizes, int n_in,
                              void* d_out, int out_size, void* d_ws, size_t ws_size,
                              hipStream_t stream) {
    const float* x     = (const float*)d_in[0];
    const float* s     = (const float*)d_in[1];
    const float* Wh    = (const float*)d_in[2];
    const float* bh    = (const float*)d_in[3];
    const float* Whalt = (const float*)d_in[4];
    const float* bhalt = (const float*)d_in[5];
    const float* Wo    = (const float*)d_in[6];
    const float* bo    = (const float*)d_in[7];
    float* out = (float*)d_out;
    float* wsb = (float*)d_ws;

    for (int i = 0; i <= K_PRE; ++i)
        k_step<<<NB, NT, 0, stream>>>(i, x, s, Wh, bh, Whalt, bhalt, wsb);

    {   // cooperative tail for T > K_PRE
        void* args[] = { (void*)&x, (void*)&Wh, (void*)&bh, (void*)&Whalt,
                         (void*)&bhalt, (void*)&wsb };
        hipLaunchCooperativeKernel((void*)k_tail, dim3(256), dim3(NT),
                                   args, 0, stream);
    }
    k_out<<<NB, NT, 0, stream>>>(Wo, bo, wsb, out);
}

// Round 15
// 212.769 us; speedup vs baseline: 1.7778x; 1.0192x over previous
//
#include <hip/hip_runtime.h>
#include <hip/hip_cooperative_groups.h>

namespace cg = cooperative_groups;

#define K_PRE 6   // device-gated pre-launched steps (bench data halts at T~3-4)
#define NB 256
#define NT 1024

// ---- ws float offsets ----
#define O_CUM    0      // cum after step j, 128 slots
#define O_DONE   128    // done after step j, 128 slots
#define O_WSUM   256
#define O_PONDER 257
#define O_AXB    512    // x-half dot + bh cache, 4096
#define O_P0     4608   // parity-0 A-partials, 4096
#define O_Q0     12800  // parity-1 A-partials, 4096
#define O_ACCH   20992  // hid accumulator, 4096
#define O_NS0    25088  // tail handoff state
#define O_NS1    29184

// Swizzled LDS index: +1 dword pad every 32 -> 2-way bank alias only (free).
__device__ __forceinline__ int zi(int c) { return c + (c >> 5); }

// ---------- k_step(i): [ns(i-1)+halt(i-1) redundant] + [A(i), BLOCK-COOPERATIVE] ----------
// 256 blocks x 1024 thr, 1 block/CU. A(i) reads rows block-cooperatively:
// all 1024 threads burst one 16KB row segment -> 256 sequential DRAM streams
// (page-local) instead of 4096 interleaved wave-streams (the 2.2 TB/s wall).
__global__ __launch_bounds__(NT) void k_step(
    int i,
    const float* __restrict__ x, const float* __restrict__ s,
    const float* __restrict__ Wh, const float* __restrict__ bh,
    const float* __restrict__ Whalt, const float* __restrict__ bhalt,
    float* __restrict__ wsb)
{
    const int tid  = threadIdx.x;
    const int lane = tid & 63;
    const int wid  = tid >> 6;

    __shared__ float zb1[4225];
    __shared__ float zb2[4225];
    __shared__ float redH[16];
    __shared__ float redR[16][16];

    float* pbW = wsb + ((i & 1) ? O_Q0 : O_P0);

    if (i == 0) {
        // zb1 <- x, zb2 <- s
        for (int k = tid; k < 4096; k += NT) { zb1[zi(k)] = x[k]; zb2[zi(k)] = s[k]; }
        __syncthreads();
        // 16 rows in 4 groups of 4; per row: x-part [1,4097) and s-part [4097,8193)
        for (int g = 0; g < 4; ++g) {
            float4 wx[4], wsv[4];
            float  px[4], ps[4];
            int    pres[4], n4s[4];
            #pragma unroll
            for (int rr = 0; rr < 4; ++rr) {
                const int row = blockIdx.x * 16 + g * 4 + rr;
                const int pre = (4 - ((row + 1) & 3)) & 3;   // both parts share pre
                const int n4  = (4096 - pre) >> 2;
                pres[rr] = pre; n4s[rr] = n4;
                const float* base = Wh + (size_t)row * 8193;
                if (tid < n4) {
                    wx[rr]  = *(const float4*)(base + 1    + pre + 4 * tid);
                    wsv[rr] = *(const float4*)(base + 4097 + pre + 4 * tid);
                }
            }
            #pragma unroll
            for (int rr = 0; rr < 4; ++rr) {
                float ax = 0.f, as = 0.f;
                const int pre = pres[rr], n4 = n4s[rr];
                if (tid < n4) {
                    const int u = pre + 4 * tid;
                    ax = wx[rr].x*zb1[zi(u)]   + wx[rr].y*zb1[zi(u+1)]
                       + wx[rr].z*zb1[zi(u+2)] + wx[rr].w*zb1[zi(u+3)];
                    as = wsv[rr].x*zb2[zi(u)]   + wsv[rr].y*zb2[zi(u+1)]
                       + wsv[rr].z*zb2[zi(u+2)] + wsv[rr].w*zb2[zi(u+3)];
                }
                if (tid == 1008 + rr) {          // peel + tail scalars, this row
                    const float* base = Wh + (size_t)(blockIdx.x*16 + g*4 + rr) * 8193;
                    for (int u = 0; u < pre; ++u)
                        { ax += base[1+u]*zb1[zi(u)]; as += base[4097+u]*zb2[zi(u)]; }
                    for (int u = pre + 4*n4; u < 4096; ++u)
                        { ax += base[1+u]*zb1[zi(u)]; as += base[4097+u]*zb2[zi(u)]; }
                }
                px[rr] = ax; ps[rr] = as;
            }
            #pragma unroll
            for (int rr = 0; rr < 4; ++rr) {
                #pragma unroll
                for (int off = 32; off; off >>= 1) {
                    px[rr] += __shfl_xor(px[rr], off, 64);
                    ps[rr] += __shfl_xor(ps[rr], off, 64);
                }
                if (lane == 0) { redR[rr][wid] = px[rr]; redR[8 + rr][wid] = ps[rr]; }
            }
            __syncthreads();
            if (tid < 4) {
                float xd = 0.f, sd = 0.f;
                #pragma unroll
                for (int j2 = 0; j2 < 16; ++j2) { xd += redR[tid][j2]; sd += redR[8+tid][j2]; }
                const int row = blockIdx.x * 16 + g * 4 + tid;
                wsb[O_AXB + row] = xd + bh[row];                       // x-half (+bias) cache
                pbW[row] = (xd + sd) + Wh[(size_t)row * 8193];         // + flag col (step 0)
            }
            __syncthreads();                      // redR reuse next group
        }
        return;
    }

    // ---- idle fast path keeps the scalar chain alive ----
    const float doneB = (i >= 2) ? wsb[O_DONE + i - 2] : 0.0f;
    if (doneB != 0.0f) {
        if (blockIdx.x == 0 && tid == 0) {
            wsb[O_CUM + i - 1]  = wsb[O_CUM + i - 2];
            wsb[O_DONE + i - 1] = 1.0f;
        }
        return;
    }
    const float cumB = (i >= 2) ? wsb[O_CUM + i - 2] : 0.0f;

    // ---- ns(i-1) = pb + bias; halt logit (redundant per block) ----
    const float* pbR  = wsb + (((i - 1) & 1) ? O_Q0 : O_P0);
    const float* bias = (i == 1) ? bh : (wsb + O_AXB);     // AXB includes bh
    float4 u0 = ((const float4*)pbR)[tid];
    float4 bb = ((const float4*)bias)[tid];
    float4 hw = ((const float4*)Whalt)[tid];
    float4 nsv;
    nsv.x = u0.x + bb.x;  nsv.y = u0.y + bb.y;
    nsv.z = u0.z + bb.z;  nsv.w = u0.w + bb.w;
    { int c = 4 * tid;                            // stage full ns into LDS
      zb1[zi(c)]   = nsv.x; zb1[zi(c+1)] = nsv.y;
      zb1[zi(c+2)] = nsv.z; zb1[zi(c+3)] = nsv.w; }
    float part = hw.x*nsv.x + hw.y*nsv.y + hw.z*nsv.z + hw.w*nsv.w;
    #pragma unroll
    for (int off = 32; off; off >>= 1) part += __shfl_xor(part, off, 64);
    if (lane == 0) redH[wid] = part;
    __syncthreads();                              // zb1(ns) + redH ready
    float logit = bhalt[0];
    #pragma unroll
    for (int j = 0; j < 16; ++j) logit += redH[j];     // identical everywhere
    const float p         = 1.0f / (1.0f + expf(-logit));
    const bool  will_halt = (cumB + p >= 0.99f) || ((i - 1) == 127);
    const float w         = will_halt ? (1.0f - cumB) : p;

    if (blockIdx.x == 0 && tid == 0) {
        wsb[O_CUM + i - 1]  = cumB + p;
        wsb[O_DONE + i - 1] = will_halt ? 1.0f : 0.0f;
        if (i == 1) wsb[O_WSUM] = w; else wsb[O_WSUM] += w;
        if (will_halt) wsb[O_PONDER] = (float)(i - 1) + 1.0f + (1.0f - cumB);
    }
    if (blockIdx.x == 0) {                        // hid accumulator, block 0
        float4* aH = reinterpret_cast<float4*>(wsb + O_ACCH);
        if (i == 1) {
            float4 t; t.x = w*nsv.x; t.y = w*nsv.y; t.z = w*nsv.z; t.w = w*nsv.w;
            aH[tid] = t;
        } else {
            float4 t = aH[tid];
            t.x += w*nsv.x; t.y += w*nsv.y; t.z += w*nsv.z; t.w += w*nsv.w;
            aH[tid] = t;
        }
    }
    if (i == K_PRE && blockIdx.x == 1)            // handoff for coop tail
        reinterpret_cast<float4*>(wsb + (((i - 1) & 1) ? O_NS1 : O_NS0))[tid] = nsv;

    // ---- A(i): 16 rows block-cooperative, 2 groups of 8 (state-half only) ----
    if (i < K_PRE && !will_halt) {
        for (int g = 0; g < 2; ++g) {
            float4 wv[8];
            float  prt[8];
            int    pres[8], n4s[8];
            #pragma unroll
            for (int rr = 0; rr < 8; ++rr) {
                const int row = blockIdx.x * 16 + g * 8 + rr;
                const int pre = (4 - ((row + 1) & 3)) & 3;
                const int n4  = (4096 - pre) >> 2;
                pres[rr] = pre; n4s[rr] = n4;
                if (tid < n4)
                    wv[rr] = *(const float4*)(Wh + (size_t)row * 8193 + 4097 + pre + 4 * tid);
            }
            #pragma unroll
            for (int rr = 0; rr < 8; ++rr) {
                float a = 0.f;
                const int pre = pres[rr], n4 = n4s[rr];
                if (tid < n4) {
                    const int u = pre + 4 * tid;
                    a = wv[rr].x*zb1[zi(u)]   + wv[rr].y*zb1[zi(u+1)]
                      + wv[rr].z*zb1[zi(u+2)] + wv[rr].w*zb1[zi(u+3)];
                }
                if (tid == 1016 + rr) {           // peel + tail scalars
                    const float* base = Wh + (size_t)(blockIdx.x*16 + g*8 + rr) * 8193 + 4097;
                    for (int u = 0; u < pre; ++u)            a += base[u] * zb1[zi(u)];
                    for (int u = pre + 4*n4; u < 4096; ++u)  a += base[u] * zb1[zi(u)];
                }
                prt[rr] = a;
            }
            #pragma unroll
            for (int rr = 0; rr < 8; ++rr) {
                #pragma unroll
                for (int off = 32; off; off >>= 1) prt[rr] += __shfl_xor(prt[rr], off, 64);
                if (lane == 0) redR[rr][wid] = prt[rr];
            }
            __syncthreads();
            if (tid < 8) {
                float d = 0.f;
                #pragma unroll
                for (int j2 = 0; j2 < 16; ++j2) d += redR[tid][j2];
                pbW[blockIdx.x * 16 + g * 8 + tid] = d;
            }
            if (g == 0) __syncthreads();          // redR reuse
        }
    }
}

// ---------- cooperative tail for T > K_PRE (instant uniform exit on bench data) ----------
__global__ __launch_bounds__(NT, 4) void k_tail(
    const float* __restrict__ x, const float* __restrict__ Wh,
    const float* __restrict__ bh, const float* __restrict__ Whalt,
    const float* __restrict__ bhalt, float* __restrict__ wsb)
{
    cg::grid_group grid = cg::this_grid();
    if (wsb[O_DONE + K_PRE - 1] != 0.0f) return;

    const int tid  = threadIdx.x;
    const int lane = tid & 63;
    const int wid  = tid >> 6;
    const int gw   = blockIdx.x * 16 + wid;

    float* ns0 = wsb + O_NS0;
    float* ns1 = wsb + O_NS1;

    __shared__ float xl[4096];
    __shared__ float red[16];
    for (int k = tid; k < 4096; k += NT) xl[k] = x[k];
    __syncthreads();

    const float* WhR   = Wh + (size_t)gw * 8193;
    const float4* wh4  = reinterpret_cast<const float4*>(Whalt);
    const float bh_r   = bh[gw];
    const float bhalt0 = bhalt[0];

    float cum = wsb[O_CUM + K_PRE - 1];
    float wsuml = 0.f, ponder = 0.f;

    for (int i = K_PRE; i < 128; ++i) {
        const float* st = (i & 1) ? ns0 : ns1;
        float*      nsc = (i & 1) ? ns1 : ns0;

        float acc = 0.0f;
        #pragma unroll 8
        for (int k = lane; k < 4096; k += 64) acc += WhR[1 + k] * xl[k];
        #pragma unroll 8
        for (int k = lane; k < 4096; k += 64) acc += WhR[4097 + k] * st[k];
        #pragma unroll
        for (int off = 32; off; off >>= 1) acc += __shfl_xor(acc, off, 64);
        if (lane == 0) nsc[gw] = acc + bh_r;
        grid.sync();

        const float4* ns4 = reinterpret_cast<const float4*>(nsc);
        float4 nv = ns4[tid], hw = wh4[tid];
        float part = hw.x*nv.x + hw.y*nv.y + hw.z*nv.z + hw.w*nv.w;
        #pragma unroll
        for (int off = 32; off; off >>= 1) part += __shfl_xor(part, off, 64);
        if (lane == 0) red[wid] = part;
        __syncthreads();
        float logit = bhalt0;
        #pragma unroll
        for (int j = 0; j < 16; ++j) logit += red[j];
        const float p         = 1.0f / (1.0f + expf(-logit));
        const bool  will_halt = (cum + p >= 0.99f) || (i == 127);
        const float w         = will_halt ? (1.0f - cum) : p;

        if (blockIdx.x == 0) {                     // hid accumulator
            float4* aH = reinterpret_cast<float4*>(wsb + O_ACCH);
            float4 t = aH[tid];
            t.x += w*nv.x; t.y += w*nv.y; t.z += w*nv.z; t.w += w*nv.w;
            aH[tid] = t;
        }
        wsuml += w;

        if (will_halt) { ponder = (float)i + 1.0f + (1.0f - cum); break; }
        cum += p;
        grid.sync();
    }

    if (blockIdx.x == 0 && tid == 0) {
        wsb[O_WSUM]  += wsuml;
        wsb[O_PONDER] = ponder;
    }
}

// ---------- k_out: out = Wo @ hid + wsum*bo (Wo once, block-cooperative) ----------
__global__ __launch_bounds__(NT) void k_out(
    const float* __restrict__ Wo, const float* __restrict__ bo,
    const float* __restrict__ wsb, float* __restrict__ out)
{
    const int tid  = threadIdx.x;
    const int lane = tid & 63;
    const int wid  = tid >> 6;

    __shared__ float zb1[4225];
    __shared__ float redR[16][16];
    for (int k = tid; k < 4096; k += NT) zb1[zi(k)] = wsb[O_ACCH + k];
    __syncthreads();

    const float wsum = wsb[O_WSUM];
    for (int g = 0; g < 2; ++g) {
        float4 wv[8];
        float  prt[8];
        #pragma unroll
        for (int rr = 0; rr < 8; ++rr) {
            const int row = blockIdx.x * 16 + g * 8 + rr;
            wv[rr] = ((const float4*)(Wo + (size_t)row * 4096))[tid];   // aligned, n4=1024
        }
        #pragma unroll
        for (int rr = 0; rr < 8; ++rr) {
            const int u = 4 * tid;
            prt[rr] = wv[rr].x*zb1[zi(u)]   + wv[rr].y*zb1[zi(u+1)]
                    + wv[rr].z*zb1[zi(u+2)] + wv[rr].w*zb1[zi(u+3)];
        }
        #pragma unroll
        for (int rr = 0; rr < 8; ++rr) {
            #pragma unroll
            for (int off = 32; off; off >>= 1) prt[rr] += __shfl_xor(prt[rr], off, 64);
            if (lane == 0) redR[rr][wid] = prt[rr];
        }
        __syncthreads();
        if (tid < 8) {
            float d = 0.f;
            #pragma unroll
            for (int j2 = 0; j2 < 16; ++j2) d += redR[tid][j2];
            const int row = blockIdx.x * 16 + g * 8 + tid;
            out[row] = d + wsum * bo[row];
        }
        if (g == 0) __syncthreads();
    }

    const int gtid = blockIdx.x * NT + tid;
    if (gtid < 4096) out[4096 + gtid] = wsb[O_ACCH + gtid];
    if (gtid == 0)   out[8192] = wsb[O_PONDER];
}

extern "C" void kernel_launch(void* const* d_in, const int* in_sizes, int n_in,
                              void* d_out, int out_size, void* d_ws, size_t ws_size,
                              hipStream_t stream) {
    const float* x     = (const float*)d_in[0];
    const float* s     = (const float*)d_in[1];
    const float* Wh    = (const float*)d_in[2];
    const float* bh    = (const float*)d_in[3];
    const float* Whalt = (const float*)d_in[4];
    const float* bhalt = (const float*)d_in[5];
    const float* Wo    = (const float*)d_in[6];
    const float* bo    = (const float*)d_in[7];
    float* out = (float*)d_out;
    float* wsb = (float*)d_ws;

    for (int i = 0; i <= K_PRE; ++i)
        k_step<<<NB, NT, 0, stream>>>(i, x, s, Wh, bh, Whalt, bhalt, wsb);

    {   // cooperative tail for T > K_PRE
        void* args[] = { (void*)&x, (void*)&Wh, (void*)&bh, (void*)&Whalt,
                         (void*)&bhalt, (void*)&wsb };
        hipLaunchCooperativeKernel((void*)k_tail, dim3(256), dim3(NT),
                                   args, 0, stream);
    }
    k_out<<<NB, NT, 0, stream>>>(Wo, bo, wsb, out);
}